// Round 8
// baseline (391.478 us; speedup 1.0000x reference)
//
#include <hip/hip_runtime.h>
#include <math.h>

#define B_    8
#define N_    1024
#define FIN   512
#define FOUT  256
#define H_    8
#define ALPHA 0.2f

#define XT (B_ * N_ * FIN)     // 4194304 x elements
#define WT (H_ * FOUT * FIN)   // 1048576 W elements

typedef short s16x8 __attribute__((ext_vector_type(8)));
typedef float f32x4 __attribute__((ext_vector_type(4)));

__device__ __forceinline__ unsigned short f2bf(float f) {
  unsigned int u = __float_as_uint(f);
  u = (u + 0x7FFFu + ((u >> 16) & 1u)) >> 16;   // round-to-nearest-even
  return (unsigned short)u;
}

// pack 4 fp32 -> 4 OCP e4m3 bytes (v_cvt_pk_fp8_f32; OCP format on gfx950)
__device__ __forceinline__ unsigned int pk4_fp8(float a, float b, float c,
                                                float d) {
  int u = __builtin_amdgcn_cvt_pk_fp8_f32(a, b, 0, false);   // bytes 0,1
  u = __builtin_amdgcn_cvt_pk_fp8_f32(c, d, u, true);        // bytes 2,3
  return (unsigned int)u;
}

// ---------------------------------------------------------------------------
// Kernel 0: fp32->bf16 convert of x,W + zero f1/f2 + byte-transposed adj pack.
// adjP layout per row (128 B): byte [q*32 + kk] = adj bits j = kk*32+q*8 ..+7
// so attn lane (quad=q) reads ONE dword per 4 kk at row*32 + q*8 + (kk>>2).
// ---------------------------------------------------------------------------
#define CVB  ((XT + WT) / 1024)          // 5120 convert blocks
#define ZRB  128                         // zero blocks
#define PKB  ((B_ * N_ * 32) / 256)      // 1024 adj-pack blocks

__global__ __launch_bounds__(256) void prep(
    const float* __restrict__ x, const float* __restrict__ W,
    const int* __restrict__ adj, unsigned short* __restrict__ xb,
    unsigned short* __restrict__ Wb, float* __restrict__ f12,
    unsigned int* __restrict__ adjP) {
  const int blk = blockIdx.x;
  if (blk >= CVB + ZRB) {    // ---- pack adj (byte-transposed) ----
    const int dw = (blk - CVB - ZRB) * 256 + threadIdx.x;  // permuted dword
    const int r = dw >> 5, pd = dw & 31;
    const int q = pd >> 3, c8 = pd & 7;                    // c8 = kk>>2
    const int* ap = adj + (size_t)r * N_;
    unsigned int out = 0;
#pragma unroll
    for (int i = 0; i < 4; ++i) {        // byte i: kk = c8*4+i
      const int jb = (c8 * 4 + i) * 32 + q * 8;
      int4 v0 = *(const int4*)(ap + jb);
      int4 v1 = *(const int4*)(ap + jb + 4);
      unsigned int byte = 0;
      byte |= (v0.x ? 1u : 0u) << 0; byte |= (v0.y ? 1u : 0u) << 1;
      byte |= (v0.z ? 1u : 0u) << 2; byte |= (v0.w ? 1u : 0u) << 3;
      byte |= (v1.x ? 1u : 0u) << 4; byte |= (v1.y ? 1u : 0u) << 5;
      byte |= (v1.z ? 1u : 0u) << 6; byte |= (v1.w ? 1u : 0u) << 7;
      out |= byte << (i * 8);
    }
    adjP[dw] = out;
    return;
  }
  if (blk >= CVB) {          // ---- zero f1/f2 ----
    const int i = (blk - CVB) * 256 + threadIdx.x;
    ((float4*)f12)[i] = make_float4(0.f, 0.f, 0.f, 0.f);
    return;
  }
  // ---- fp32 -> bf16 ----
  const int i = (blk * 256 + threadIdx.x) * 4;
  const float* src;
  unsigned short* dst;
  int off;
  if (i < XT) { src = x; dst = xb; off = i; }
  else        { src = W; dst = Wb; off = i - XT; }
  float4 v = *(const float4*)(src + off);
  ushort4 s;
  s.x = f2bf(v.x); s.y = f2bf(v.y); s.z = f2bf(v.z); s.w = f2bf(v.w);
  *(ushort4*)(dst + off) = s;
}

// ---------------------------------------------------------------------------
// Kernel 1: projection GEMM, LDS-staged bf16 MFMA, fp8 transposed output.
// (unchanged from R6)
// ---------------------------------------------------------------------------
__global__ __launch_bounds__(256) void proj_mfma(
    const unsigned short* __restrict__ xb, const unsigned short* __restrict__ Wb,
    const float* __restrict__ a1, const float* __restrict__ a2,
    unsigned char* __restrict__ htq, float* __restrict__ f1,
    float* __restrict__ f2) {
  __shared__ __align__(16) unsigned short As[128 * 64];  // 16 KB
  __shared__ __align__(16) unsigned short Bs[64 * 64];   //  8 KB
  const int gid = blockIdx.x;
  const int b = gid & 7;
  const int mt_ = (gid >> 3) & 7;
  const int ot_ = (gid >> 6) & 3;
  const int h = gid >> 8;
  const int hb = h * B_ + b;
  const int m0 = mt_ * 128, o0 = ot_ * 64;
  const int t = threadIdx.x, w = t >> 6, lane = t & 63;
  const int col = lane & 15, quad = lane >> 4;

  const int srow = t >> 3;
  const int sslot = t & 7;
  const int sseg = sslot ^ (srow & 7);
  const unsigned short* agp = xb + (size_t)(b * N_ + m0 + srow) * FIN + sseg * 8;
  const unsigned short* bgp = Wb + (size_t)(h * FOUT + o0 + srow) * FIN + sseg * 8;

  f32x4 acc[2][4];
  const f32x4 z4 = {0.f, 0.f, 0.f, 0.f};
#pragma unroll
  for (int mt = 0; mt < 2; ++mt)
#pragma unroll
    for (int ot = 0; ot < 4; ++ot) acc[mt][ot] = z4;

  s16x8 pa[4], pb[2];
#pragma unroll
  for (int i2 = 0; i2 < 4; ++i2) pa[i2] = *(const s16x8*)(agp + (size_t)i2 * 32 * FIN);
#pragma unroll
  for (int i2 = 0; i2 < 2; ++i2) pb[i2] = *(const s16x8*)(bgp + (size_t)i2 * 32 * FIN);

  for (int it = 0; it < FIN / 64; ++it) {
    __syncthreads();
#pragma unroll
    for (int i2 = 0; i2 < 4; ++i2)
      *(s16x8*)&As[(i2 * 32 + srow) * 64 + sslot * 8] = pa[i2];
#pragma unroll
    for (int i2 = 0; i2 < 2; ++i2)
      *(s16x8*)&Bs[(i2 * 32 + srow) * 64 + sslot * 8] = pb[i2];
    __syncthreads();
    if (it < FIN / 64 - 1) {
      const int k0 = (it + 1) * 64;
#pragma unroll
      for (int i2 = 0; i2 < 4; ++i2)
        pa[i2] = *(const s16x8*)(agp + (size_t)i2 * 32 * FIN + k0);
#pragma unroll
      for (int i2 = 0; i2 < 2; ++i2)
        pb[i2] = *(const s16x8*)(bgp + (size_t)i2 * 32 * FIN + k0);
    }
#pragma unroll
    for (int kb = 0; kb < 2; ++kb) {
      s16x8 af[2], bf[4];
#pragma unroll
      for (int mt = 0; mt < 2; ++mt) {
        const int row = w * 32 + mt * 16 + col;
        af[mt] = *(const s16x8*)&As[row * 64 + ((kb * 4 + quad) ^ (row & 7)) * 8];
      }
#pragma unroll
      for (int ot = 0; ot < 4; ++ot) {
        const int row = ot * 16 + col;
        bf[ot] = *(const s16x8*)&Bs[row * 64 + ((kb * 4 + quad) ^ (row & 7)) * 8];
      }
#pragma unroll
      for (int mt = 0; mt < 2; ++mt)
#pragma unroll
        for (int ot = 0; ot < 4; ++ot)
          acc[mt][ot] = __builtin_amdgcn_mfma_f32_16x16x32_bf16(af[mt], bf[ot],
                                                                acc[mt][ot], 0, 0, 0);
    }
  }

  float pf1[2][4] = {{0.f}}, pf2[2][4] = {{0.f}};
#pragma unroll
  for (int mt = 0; mt < 2; ++mt) {
#pragma unroll
    for (int ot = 0; ot < 4; ++ot) {
      const int o = o0 + ot * 16 + col;
      const float va1 = a1[h * FOUT + o], va2 = a2[h * FOUT + o];
      const int m = m0 + w * 32 + mt * 16 + quad * 4;
      const unsigned int q =
          pk4_fp8(acc[mt][ot][0], acc[mt][ot][1], acc[mt][ot][2], acc[mt][ot][3]);
      *(unsigned int*)(htq + (size_t)(hb * FOUT + o) * N_ + m) = q;
#pragma unroll
      for (int r = 0; r < 4; ++r) {
        pf1[mt][r] += acc[mt][ot][r] * va1;
        pf2[mt][r] += acc[mt][ot][r] * va2;
      }
    }
  }
#pragma unroll
  for (int off = 1; off <= 8; off <<= 1)
#pragma unroll
    for (int mt = 0; mt < 2; ++mt)
#pragma unroll
      for (int r = 0; r < 4; ++r) {
        pf1[mt][r] += __shfl_xor(pf1[mt][r], off);
        pf2[mt][r] += __shfl_xor(pf2[mt][r], off);
      }
  if (col == 0) {
#pragma unroll
    for (int mt = 0; mt < 2; ++mt)
#pragma unroll
      for (int r = 0; r < 4; ++r) {
        const int n = m0 + w * 32 + mt * 16 + quad * 4 + r;
        atomicAdd(&f1[hb * N_ + n], pf1[mt][r]);
        atomicAdd(&f2[hb * N_ + n], pf2[mt][r]);
      }
  }
}

// ---------------------------------------------------------------------------
// Kernel 1b: M2[hb] = max_j f2[hb][j]. One wave per hb.
// ---------------------------------------------------------------------------
__global__ __launch_bounds__(256) void m2k(const float* __restrict__ f2,
                                           float* __restrict__ M2) {
  const int hb = blockIdx.x * 4 + (threadIdx.x >> 6);
  const int lane = threadIdx.x & 63;
  const float* fp = f2 + (size_t)hb * N_;
  float m = -3.0e38f;
#pragma unroll
  for (int c = 0; c < 16; ++c) m = fmaxf(m, fp[lane + c * 64]);
#pragma unroll
  for (int off = 32; off; off >>= 1) m = fmaxf(m, __shfl_xor(m, off));
  if (lane == 0) M2[hb] = m;
}

// ---------------------------------------------------------------------------
// Kernel 2: BARRIER-FREE fused attention. NO LDS. 256 thr = 4 independent
// waves. Wave: 16 rows x 128 o-cols x 2 heads. Lane (col,quad) computes its
// own A-fragment scores in registers (row=col, k=quad*8+j), packs to fp8,
// feeds 8 B-tile MFMAs + ones-column (denominator). adj bits come from the
// byte-transposed bitmask: one L1-hot dword per 4 kk.
// Grid 1024 = (b, 4 head-groups, 2 o-halves, 16 i-blocks of 64 rows).
// ---------------------------------------------------------------------------
__global__ __launch_bounds__(256) void attn_fused(
    const unsigned char* __restrict__ htq, const float* __restrict__ f1,
    const float* __restrict__ f2, const unsigned int* __restrict__ adjP,
    const float* __restrict__ M2g,
    float* __restrict__ p0, float* __restrict__ p1, float* __restrict__ p2,
    float* __restrict__ p3) {
  const int id = blockIdx.x;
  const int b = id & 7;                 // XCD-keyed
  const int g0 = (id >> 3) & 3;        // heads {2g0, 2g0+1}
  const int oi = (id >> 5) & 1;        // o-half: [oi*128, +128)
  const int it = id >> 6;              // i-block (64 rows)
  const int w = threadIdx.x >> 6, lane = threadIdx.x & 63;
  const int col = lane & 15, quad = lane >> 4;
  const int i0w = it * 64 + w * 16;    // this wave's 16 rows
  const int row = i0w + col;           // lane's score row

  // adj dwords for (row, quad): 8 dwords at adjP[row*32 + quad*8 + k4]
  const unsigned int* adp = adjP + ((size_t)(b * N_ + row) << 5) + quad * 8;

  float hsum[8][4];
#pragma unroll
  for (int t = 0; t < 8; ++t)
#pragma unroll
    for (int r = 0; r < 4; ++r) hsum[t][r] = 0.f;

  const long ones = 0x3838383838383838L;   // 8x fp8 e4m3 1.0

  for (int hh = 0; hh < 2; ++hh) {
    const int hb = (g0 * 2 + hh) * B_ + b;
    const float f1i = f1[(size_t)hb * N_ + row];
    const float tb = f1i + M2g[hb];
    const float mhat = fmaxf(tb, ALPHA * tb);   // >= leaky(f1i+f2j) for all j
    const float* f2p = f2 + (size_t)hb * N_ + quad * 8;
    const unsigned char* bp =
        htq + (size_t)(hb * FOUT + oi * 128 + col) * N_ + quad * 8;

    f32x4 acc[8], accs;
    const f32x4 z4 = {0.f, 0.f, 0.f, 0.f};
    accs = z4;
#pragma unroll
    for (int t = 0; t < 8; ++t) acc[t] = z4;

    for (int k4 = 0; k4 < 8; ++k4) {         // 4 kk per adj dword
      const unsigned int ad = adp[k4];
#pragma unroll
      for (int k2 = 0; k2 < 4; ++k2) {
        const int kk = k4 * 4 + k2;
        const unsigned int ab = (ad >> (k2 * 8)) & 0xFFu;
        // scores for k = kk*32 + quad*8 + (0..7)
        const float4 fA = *(const float4*)(f2p + kk * 32);
        const float4 fB = *(const float4*)(f2p + kk * 32 + 4);
        float ex[8];
#pragma unroll
        for (int j = 0; j < 8; ++j) {
          const float fv = j < 4 ? ((const float*)&fA)[j]
                                 : ((const float*)&fB)[j - 4];
          const float tt = f1i + fv;
          const float l = fmaxf(tt, ALPHA * tt);
          const float p = __expf(l - mhat);
          ex[j] = ((ab >> j) & 1u) ? p : 0.f;
        }
        const unsigned int lo = pk4_fp8(ex[0], ex[1], ex[2], ex[3]);
        const unsigned int hi = pk4_fp8(ex[4], ex[5], ex[6], ex[7]);
        const long af = (long)(((unsigned long long)hi << 32) | lo);
        accs = __builtin_amdgcn_mfma_f32_16x16x32_fp8_fp8(af, ones, accs, 0, 0, 0);
#pragma unroll
        for (int t = 0; t < 8; ++t) {
          const long bf = *(const long*)(bp + (size_t)t * 16 * N_ + kk * 32);
          acc[t] = __builtin_amdgcn_mfma_f32_16x16x32_fp8_fp8(af, bf, acc[t],
                                                              0, 0, 0);
        }
      }
    }

    // normalize (denom from ones-column, same quantized weights), ELU, sum
#pragma unroll
    for (int r = 0; r < 4; ++r) {
      const float inv = 1.0f / accs[r];
#pragma unroll
      for (int t = 0; t < 8; ++t) {
        const float oh = acc[t][r] * inv;
        hsum[t][r] += oh > 0.f ? oh : __expf(oh) - 1.f;
      }
    }
  }

  // ---- write head-group partial: row i0w+quad*4+r, col oi*128+t*16+col ----
  float* pdst = (g0 == 0) ? p0 : (g0 == 1) ? p1 : (g0 == 2) ? p2 : p3;
#pragma unroll
  for (int t = 0; t < 8; ++t)
#pragma unroll
    for (int r = 0; r < 4; ++r) {
      const int orow = i0w + quad * 4 + r;
      pdst[(size_t)(b * N_ + orow) * FOUT + oi * 128 + t * 16 + col] =
          hsum[t][r];
    }
}

// ---------------------------------------------------------------------------
// Kernel 3: sum 4 head-group partials + log_softmax over o. Wave per row.
// ---------------------------------------------------------------------------
__global__ __launch_bounds__(256) void logsm(
    const float* __restrict__ p0, const float* __restrict__ p1,
    const float* __restrict__ p2, const float* __restrict__ p3,
    float* __restrict__ out) {
  const int row = blockIdx.x * 4 + (threadIdx.x >> 6);
  const int lane = threadIdx.x & 63;
  const size_t base = (size_t)row * FOUT;
  float v[4];
  float m = -3.0e38f;
#pragma unroll
  for (int c = 0; c < 4; ++c) {
    const size_t idx = base + c * 64 + lane;
    v[c] = p0[idx] + p1[idx] + p2[idx] + p3[idx];
    m = fmaxf(m, v[c]);
  }
#pragma unroll
  for (int off = 32; off; off >>= 1) m = fmaxf(m, __shfl_xor(m, off));
  float s = 0.f;
#pragma unroll
  for (int c = 0; c < 4; ++c) s += __expf(v[c] - m);
#pragma unroll
  for (int off = 32; off; off >>= 1) s += __shfl_xor(s, off);
  const float lg = m + logf(s);
#pragma unroll
  for (int c = 0; c < 4; ++c)
    out[base + c * 64 + lane] = v[c] - lg;
}

// ---------------------------------------------------------------------------
extern "C" void kernel_launch(void* const* d_in, const int* in_sizes, int n_in,
                              void* d_out, int out_size, void* d_ws,
                              size_t ws_size, hipStream_t stream) {
  const float* x   = (const float*)d_in[0];
  const int*   adj = (const int*)d_in[1];
  const float* W   = (const float*)d_in[2];
  const float* a1  = (const float*)d_in[3];
  const float* a2  = (const float*)d_in[4];
  float* out = (float*)d_out;

  unsigned char* htq = (unsigned char*)d_ws;                          // 16 MB fp8 h^T
  unsigned short* xb = (unsigned short*)(htq + (size_t)H_ * B_ * FOUT * N_); // 8 MB
  unsigned short* Wb = xb + (size_t)XT;                               // 2 MB
  float* f1 = (float*)(Wb + (size_t)WT);                              // 256 KB
  float* f2 = f1 + (size_t)H_ * B_ * N_;                              // 256 KB
  float* part2 = f2 + (size_t)H_ * B_ * N_;                           // 8 MB
  float* part3 = part2 + (size_t)B_ * N_ * FOUT;                      // 8 MB
  unsigned int* adjP = (unsigned int*)(part3 + (size_t)B_ * N_ * FOUT); // 1 MB
  float* M2 = (float*)(adjP + (size_t)B_ * N_ * 32);                  // 256 B
  float* part1 = (float*)xb;   // xb dead after proj_mfma (8 MB reuse)

  prep<<<CVB + ZRB + PKB, 256, 0, stream>>>(x, W, adj, xb, Wb, f1, adjP);

  proj_mfma<<<2048, 256, 0, stream>>>(xb, Wb, a1, a2, htq, f1, f2);

  m2k<<<16, 256, 0, stream>>>(f2, M2);

  attn_fused<<<1024, 256, 0, stream>>>(htq, f1, f2, adjP, M2,
                                       out, part1, part2, part3);

  logsm<<<(B_ * N_) / 4, 256, 0, stream>>>(out, part1, part2, part3, out);
}

// Round 9
// 272.787 us; speedup vs baseline: 1.4351x; 1.4351x over previous
//
#include <hip/hip_runtime.h>
#include <math.h>

#define B_    8
#define N_    1024
#define FIN   512
#define FOUT  256
#define H_    8
#define ALPHA 0.2f

#define XT (B_ * N_ * FIN)     // 4194304 x elements
#define WT (H_ * FOUT * FIN)   // 1048576 W elements

typedef short s16x8 __attribute__((ext_vector_type(8)));
typedef float f32x4 __attribute__((ext_vector_type(4)));

__device__ __forceinline__ unsigned short f2bf(float f) {
  unsigned int u = __float_as_uint(f);
  u = (u + 0x7FFFu + ((u >> 16) & 1u)) >> 16;   // round-to-nearest-even
  return (unsigned short)u;
}

// pack 4 fp32 -> 4 OCP e4m3 bytes (v_cvt_pk_fp8_f32; OCP format on gfx950)
__device__ __forceinline__ unsigned int pk4_fp8(float a, float b, float c,
                                                float d) {
  int u = __builtin_amdgcn_cvt_pk_fp8_f32(a, b, 0, false);   // bytes 0,1
  u = __builtin_amdgcn_cvt_pk_fp8_f32(c, d, u, true);        // bytes 2,3
  return (unsigned int)u;
}

// ---------------------------------------------------------------------------
// htq layout: fragment-interleaved for the PV MFMA B-operand.
// frag(hb, otg, kk) = 512 B block at ((hb*16 + otg)*32 + kk) * 512.
// Byte (quad*128 + col*8 + j) holds h[hb][k = kk*32+quad*8+j][o = otg*16+col].
// A wave's B-load is then base + lane*8: ONE coalesced 512B load per (t,kk).
// ---------------------------------------------------------------------------

// ---------------------------------------------------------------------------
// Kernel 0: fp32->bf16 convert of x,W + zero f1/f2 + byte-transposed adj pack.
// adjP layout per row (128 B): byte [q*32 + kk] = adj bits j = kk*32+q*8 ..+7
// ---------------------------------------------------------------------------
#define CVB  ((XT + WT) / 1024)          // 5120 convert blocks
#define ZRB  128                         // zero blocks
#define PKB  ((B_ * N_ * 32) / 256)      // 1024 adj-pack blocks

__global__ __launch_bounds__(256) void prep(
    const float* __restrict__ x, const float* __restrict__ W,
    const int* __restrict__ adj, unsigned short* __restrict__ xb,
    unsigned short* __restrict__ Wb, float* __restrict__ f12,
    unsigned int* __restrict__ adjP) {
  const int blk = blockIdx.x;
  if (blk >= CVB + ZRB) {    // ---- pack adj (byte-transposed) ----
    const int dw = (blk - CVB - ZRB) * 256 + threadIdx.x;  // permuted dword
    const int r = dw >> 5, pd = dw & 31;
    const int q = pd >> 3, c8 = pd & 7;                    // c8 = kk>>2
    const int* ap = adj + (size_t)r * N_;
    unsigned int out = 0;
#pragma unroll
    for (int i = 0; i < 4; ++i) {        // byte i: kk = c8*4+i
      const int jb = (c8 * 4 + i) * 32 + q * 8;
      int4 v0 = *(const int4*)(ap + jb);
      int4 v1 = *(const int4*)(ap + jb + 4);
      unsigned int byte = 0;
      byte |= (v0.x ? 1u : 0u) << 0; byte |= (v0.y ? 1u : 0u) << 1;
      byte |= (v0.z ? 1u : 0u) << 2; byte |= (v0.w ? 1u : 0u) << 3;
      byte |= (v1.x ? 1u : 0u) << 4; byte |= (v1.y ? 1u : 0u) << 5;
      byte |= (v1.z ? 1u : 0u) << 6; byte |= (v1.w ? 1u : 0u) << 7;
      out |= byte << (i * 8);
    }
    adjP[dw] = out;
    return;
  }
  if (blk >= CVB) {          // ---- zero f1/f2 ----
    const int i = (blk - CVB) * 256 + threadIdx.x;
    ((float4*)f12)[i] = make_float4(0.f, 0.f, 0.f, 0.f);
    return;
  }
  // ---- fp32 -> bf16 ----
  const int i = (blk * 256 + threadIdx.x) * 4;
  const float* src;
  unsigned short* dst;
  int off;
  if (i < XT) { src = x; dst = xb; off = i; }
  else        { src = W; dst = Wb; off = i - XT; }
  float4 v = *(const float4*)(src + off);
  ushort4 s;
  s.x = f2bf(v.x); s.y = f2bf(v.y); s.z = f2bf(v.z); s.w = f2bf(v.w);
  *(ushort4*)(dst + off) = s;
}

// ---------------------------------------------------------------------------
// Kernel 1: projection GEMM, LDS-staged bf16 MFMA.
// Output: fragment-interleaved fp8 htq (see layout above) — the epilogue
// store is now 256B-contiguous per instr (was 16 scattered lines).
// ---------------------------------------------------------------------------
__global__ __launch_bounds__(256) void proj_mfma(
    const unsigned short* __restrict__ xb, const unsigned short* __restrict__ Wb,
    const float* __restrict__ a1, const float* __restrict__ a2,
    unsigned char* __restrict__ htq, float* __restrict__ f1,
    float* __restrict__ f2) {
  __shared__ __align__(16) unsigned short As[128 * 64];  // 16 KB
  __shared__ __align__(16) unsigned short Bs[64 * 64];   //  8 KB
  const int gid = blockIdx.x;
  const int b = gid & 7;
  const int mt_ = (gid >> 3) & 7;
  const int ot_ = (gid >> 6) & 3;
  const int h = gid >> 8;
  const int hb = h * B_ + b;
  const int m0 = mt_ * 128, o0 = ot_ * 64;
  const int t = threadIdx.x, w = t >> 6, lane = t & 63;
  const int col = lane & 15, quad = lane >> 4;

  const int srow = t >> 3;
  const int sslot = t & 7;
  const int sseg = sslot ^ (srow & 7);
  const unsigned short* agp = xb + (size_t)(b * N_ + m0 + srow) * FIN + sseg * 8;
  const unsigned short* bgp = Wb + (size_t)(h * FOUT + o0 + srow) * FIN + sseg * 8;

  f32x4 acc[2][4];
  const f32x4 z4 = {0.f, 0.f, 0.f, 0.f};
#pragma unroll
  for (int mt = 0; mt < 2; ++mt)
#pragma unroll
    for (int ot = 0; ot < 4; ++ot) acc[mt][ot] = z4;

  s16x8 pa[4], pb[2];
#pragma unroll
  for (int i2 = 0; i2 < 4; ++i2) pa[i2] = *(const s16x8*)(agp + (size_t)i2 * 32 * FIN);
#pragma unroll
  for (int i2 = 0; i2 < 2; ++i2) pb[i2] = *(const s16x8*)(bgp + (size_t)i2 * 32 * FIN);

  for (int it = 0; it < FIN / 64; ++it) {
    __syncthreads();
#pragma unroll
    for (int i2 = 0; i2 < 4; ++i2)
      *(s16x8*)&As[(i2 * 32 + srow) * 64 + sslot * 8] = pa[i2];
#pragma unroll
    for (int i2 = 0; i2 < 2; ++i2)
      *(s16x8*)&Bs[(i2 * 32 + srow) * 64 + sslot * 8] = pb[i2];
    __syncthreads();
    if (it < FIN / 64 - 1) {
      const int k0 = (it + 1) * 64;
#pragma unroll
      for (int i2 = 0; i2 < 4; ++i2)
        pa[i2] = *(const s16x8*)(agp + (size_t)i2 * 32 * FIN + k0);
#pragma unroll
      for (int i2 = 0; i2 < 2; ++i2)
        pb[i2] = *(const s16x8*)(bgp + (size_t)i2 * 32 * FIN + k0);
    }
#pragma unroll
    for (int kb = 0; kb < 2; ++kb) {
      s16x8 af[2], bf[4];
#pragma unroll
      for (int mt = 0; mt < 2; ++mt) {
        const int row = w * 32 + mt * 16 + col;
        af[mt] = *(const s16x8*)&As[row * 64 + ((kb * 4 + quad) ^ (row & 7)) * 8];
      }
#pragma unroll
      for (int ot = 0; ot < 4; ++ot) {
        const int row = ot * 16 + col;
        bf[ot] = *(const s16x8*)&Bs[row * 64 + ((kb * 4 + quad) ^ (row & 7)) * 8];
      }
#pragma unroll
      for (int mt = 0; mt < 2; ++mt)
#pragma unroll
        for (int ot = 0; ot < 4; ++ot)
          acc[mt][ot] = __builtin_amdgcn_mfma_f32_16x16x32_bf16(af[mt], bf[ot],
                                                                acc[mt][ot], 0, 0, 0);
    }
  }

  // epilogue: fragment-interleaved fp8 store + fused f1/f2 partials.
  // lane holds (o = o0+ot*16+col, k = m0+w*32+mt*16+quad*4+r, r=0..3):
  //   kk  = m0/32 + w  (mt*16+quad*4 < 32)
  //   quad_frag = 2*mt + (quad>>1),  j = (quad&1)*4 + r
  const int kkw = (m0 >> 5) + w;
  float pf1[2][4] = {{0.f}}, pf2[2][4] = {{0.f}};
#pragma unroll
  for (int mt = 0; mt < 2; ++mt) {
#pragma unroll
    for (int ot = 0; ot < 4; ++ot) {
      const int o = o0 + ot * 16 + col;
      const float va1 = a1[h * FOUT + o], va2 = a2[h * FOUT + o];
      const int otg = (o0 >> 4) + ot;
      unsigned char* fb =
          htq + (((size_t)(hb * 16 + otg) * 32 + kkw) << 9);
      const unsigned int q =
          pk4_fp8(acc[mt][ot][0], acc[mt][ot][1], acc[mt][ot][2], acc[mt][ot][3]);
      *(unsigned int*)(fb + (2 * mt + (quad >> 1)) * 128 + col * 8 +
                       (quad & 1) * 4) = q;
#pragma unroll
      for (int r = 0; r < 4; ++r) {
        pf1[mt][r] += acc[mt][ot][r] * va1;
        pf2[mt][r] += acc[mt][ot][r] * va2;
      }
    }
  }
#pragma unroll
  for (int off = 1; off <= 8; off <<= 1)
#pragma unroll
    for (int mt = 0; mt < 2; ++mt)
#pragma unroll
      for (int r = 0; r < 4; ++r) {
        pf1[mt][r] += __shfl_xor(pf1[mt][r], off);
        pf2[mt][r] += __shfl_xor(pf2[mt][r], off);
      }
  if (col == 0) {
#pragma unroll
    for (int mt = 0; mt < 2; ++mt)
#pragma unroll
      for (int r = 0; r < 4; ++r) {
        const int n = m0 + w * 32 + mt * 16 + quad * 4 + r;
        atomicAdd(&f1[hb * N_ + n], pf1[mt][r]);
        atomicAdd(&f2[hb * N_ + n], pf2[mt][r]);
      }
  }
}

// ---------------------------------------------------------------------------
// Kernel 1b: M2[hb] = max_j f2[hb][j]. One wave per hb.
// ---------------------------------------------------------------------------
__global__ __launch_bounds__(256) void m2k(const float* __restrict__ f2,
                                           float* __restrict__ M2) {
  const int hb = blockIdx.x * 4 + (threadIdx.x >> 6);
  const int lane = threadIdx.x & 63;
  const float* fp = f2 + (size_t)hb * N_;
  float m = -3.0e38f;
#pragma unroll
  for (int c = 0; c < 16; ++c) m = fmaxf(m, fp[lane + c * 64]);
#pragma unroll
  for (int off = 32; off; off >>= 1) m = fmaxf(m, __shfl_xor(m, off));
  if (lane == 0) M2[hb] = m;
}

// ---------------------------------------------------------------------------
// Kernel 2: BARRIER-FREE fused attention, coalesced B-loads.
// 256 thr = 4 independent waves; wave: 16 rows x 128 o-cols x 2 heads.
// Lane computes its own A-fragment scores in registers, packs fp8, feeds
// 8 B-tile MFMAs + ones-column. B-fragments come from the interleaved htq:
// base + t*16384 + kk*512 + lane*8 — one 512B coalesced load per (t,kk).
// Grid 1024 = (b, 4 head-groups, 2 o-halves, 16 i-blocks of 64 rows).
// ---------------------------------------------------------------------------
__global__ __launch_bounds__(256) void attn_fused(
    const unsigned char* __restrict__ htq, const float* __restrict__ f1,
    const float* __restrict__ f2, const unsigned int* __restrict__ adjP,
    const float* __restrict__ M2g,
    float* __restrict__ p0, float* __restrict__ p1, float* __restrict__ p2,
    float* __restrict__ p3) {
  const int id = blockIdx.x;
  const int b = id & 7;                 // XCD-keyed
  const int g0 = (id >> 3) & 3;        // heads {2g0, 2g0+1}
  const int oi = (id >> 5) & 1;        // o-half: [oi*128, +128)
  const int it = id >> 6;              // i-block (64 rows)
  const int w = threadIdx.x >> 6, lane = threadIdx.x & 63;
  const int col = lane & 15, quad = lane >> 4;
  const int i0w = it * 64 + w * 16;    // this wave's 16 rows
  const int row = i0w + col;           // lane's score row

  // adj dwords for (row, quad): 8 dwords at adjP[row*32 + quad*8 + k4]
  const unsigned int* adp = adjP + ((size_t)(b * N_ + row) << 5) + quad * 8;

  float hsum[8][4];
#pragma unroll
  for (int t = 0; t < 8; ++t)
#pragma unroll
    for (int r = 0; r < 4; ++r) hsum[t][r] = 0.f;

  const long ones = 0x3838383838383838L;   // 8x fp8 e4m3 1.0

  for (int hh = 0; hh < 2; ++hh) {
    const int hb = (g0 * 2 + hh) * B_ + b;
    const float f1i = f1[(size_t)hb * N_ + row];
    const float tb = f1i + M2g[hb];
    const float mhat = fmaxf(tb, ALPHA * tb);   // >= leaky(f1i+f2j) for all j
    const float* f2p = f2 + (size_t)hb * N_ + quad * 8;
    // fragment base for this head's o-half, lane-linear
    const unsigned char* bp =
        htq + (((size_t)(hb * 16 + oi * 8) * 32) << 9) + lane * 8;

    f32x4 acc[8], accs;
    const f32x4 z4 = {0.f, 0.f, 0.f, 0.f};
    accs = z4;
#pragma unroll
    for (int t = 0; t < 8; ++t) acc[t] = z4;

    for (int k4 = 0; k4 < 8; ++k4) {         // 4 kk per adj dword
      const unsigned int ad = adp[k4];
#pragma unroll
      for (int k2 = 0; k2 < 4; ++k2) {
        const int kk = k4 * 4 + k2;
        const unsigned int ab = (ad >> (k2 * 8)) & 0xFFu;
        // scores for k = kk*32 + quad*8 + (0..7)
        const float4 fA = *(const float4*)(f2p + kk * 32);
        const float4 fB = *(const float4*)(f2p + kk * 32 + 4);
        float ex[8];
#pragma unroll
        for (int j = 0; j < 8; ++j) {
          const float fv = j < 4 ? ((const float*)&fA)[j]
                                 : ((const float*)&fB)[j - 4];
          const float tt = f1i + fv;
          const float l = fmaxf(tt, ALPHA * tt);
          const float p = __expf(l - mhat);
          ex[j] = ((ab >> j) & 1u) ? p : 0.f;
        }
        const unsigned int lo = pk4_fp8(ex[0], ex[1], ex[2], ex[3]);
        const unsigned int hi = pk4_fp8(ex[4], ex[5], ex[6], ex[7]);
        const long af = (long)(((unsigned long long)hi << 32) | lo);
        accs = __builtin_amdgcn_mfma_f32_16x16x32_fp8_fp8(af, ones, accs, 0, 0, 0);
#pragma unroll
        for (int t = 0; t < 8; ++t) {
          const long bf = *(const long*)(bp + t * 16384 + kk * 512);
          acc[t] = __builtin_amdgcn_mfma_f32_16x16x32_fp8_fp8(af, bf, acc[t],
                                                              0, 0, 0);
        }
      }
    }

    // normalize (denom from ones-column, same quantized weights), ELU, sum
#pragma unroll
    for (int r = 0; r < 4; ++r) {
      const float inv = 1.0f / accs[r];
#pragma unroll
      for (int t = 0; t < 8; ++t) {
        const float oh = acc[t][r] * inv;
        hsum[t][r] += oh > 0.f ? oh : __expf(oh) - 1.f;
      }
    }
  }

  // ---- write head-group partial: row i0w+quad*4+r, col oi*128+t*16+col ----
  float* pdst = (g0 == 0) ? p0 : (g0 == 1) ? p1 : (g0 == 2) ? p2 : p3;
#pragma unroll
  for (int t = 0; t < 8; ++t)
#pragma unroll
    for (int r = 0; r < 4; ++r) {
      const int orow = i0w + quad * 4 + r;
      pdst[(size_t)(b * N_ + orow) * FOUT + oi * 128 + t * 16 + col] =
          hsum[t][r];
    }
}

// ---------------------------------------------------------------------------
// Kernel 3: sum 4 head-group partials + log_softmax over o. Wave per row.
// ---------------------------------------------------------------------------
__global__ __launch_bounds__(256) void logsm(
    const float* __restrict__ p0, const float* __restrict__ p1,
    const float* __restrict__ p2, const float* __restrict__ p3,
    float* __restrict__ out) {
  const int row = blockIdx.x * 4 + (threadIdx.x >> 6);
  const int lane = threadIdx.x & 63;
  const size_t base = (size_t)row * FOUT;
  float v[4];
  float m = -3.0e38f;
#pragma unroll
  for (int c = 0; c < 4; ++c) {
    const size_t idx = base + c * 64 + lane;
    v[c] = p0[idx] + p1[idx] + p2[idx] + p3[idx];
    m = fmaxf(m, v[c]);
  }
#pragma unroll
  for (int off = 32; off; off >>= 1) m = fmaxf(m, __shfl_xor(m, off));
  float s = 0.f;
#pragma unroll
  for (int c = 0; c < 4; ++c) s += __expf(v[c] - m);
#pragma unroll
  for (int off = 32; off; off >>= 1) s += __shfl_xor(s, off);
  const float lg = m + logf(s);
#pragma unroll
  for (int c = 0; c < 4; ++c)
    out[base + c * 64 + lane] = v[c] - lg;
}

// ---------------------------------------------------------------------------
extern "C" void kernel_launch(void* const* d_in, const int* in_sizes, int n_in,
                              void* d_out, int out_size, void* d_ws,
                              size_t ws_size, hipStream_t stream) {
  const float* x   = (const float*)d_in[0];
  const int*   adj = (const int*)d_in[1];
  const float* W   = (const float*)d_in[2];
  const float* a1  = (const float*)d_in[3];
  const float* a2  = (const float*)d_in[4];
  float* out = (float*)d_out;

  unsigned char* htq = (unsigned char*)d_ws;                          // 16 MB fp8 h (frag-interleaved)
  unsigned short* xb = (unsigned short*)(htq + (size_t)H_ * B_ * FOUT * N_); // 8 MB
  unsigned short* Wb = xb + (size_t)XT;                               // 2 MB
  float* f1 = (float*)(Wb + (size_t)WT);                              // 256 KB
  float* f2 = f1 + (size_t)H_ * B_ * N_;                              // 256 KB
  float* part2 = f2 + (size_t)H_ * B_ * N_;                           // 8 MB
  float* part3 = part2 + (size_t)B_ * N_ * FOUT;                      // 8 MB
  unsigned int* adjP = (unsigned int*)(part3 + (size_t)B_ * N_ * FOUT); // 1 MB
  float* M2 = (float*)(adjP + (size_t)B_ * N_ * 32);                  // 256 B
  float* part1 = (float*)xb;   // xb dead after proj_mfma (8 MB reuse)

  prep<<<CVB + ZRB + PKB, 256, 0, stream>>>(x, W, adj, xb, Wb, f1, adjP);

  proj_mfma<<<2048, 256, 0, stream>>>(xb, Wb, a1, a2, htq, f1, f2);

  m2k<<<16, 256, 0, stream>>>(f2, M2);

  attn_fused<<<1024, 256, 0, stream>>>(htq, f1, f2, adjP, M2,
                                       out, part1, part2, part3);

  logsm<<<(B_ * N_) / 4, 256, 0, stream>>>(out, part1, part2, part3, out);
}

// Round 10
// 234.818 us; speedup vs baseline: 1.6672x; 1.1617x over previous
//
#include <hip/hip_runtime.h>
#include <math.h>

#define B_    8
#define N_    1024
#define FIN   512
#define FOUT  256
#define H_    8
#define ALPHA 0.2f

#define XT (B_ * N_ * FIN)     // 4194304 x elements
#define WT (H_ * FOUT * FIN)   // 1048576 W elements

typedef short s16x8 __attribute__((ext_vector_type(8)));
typedef float f32x4 __attribute__((ext_vector_type(4)));

__device__ __forceinline__ unsigned short f2bf(float f) {
  unsigned int u = __float_as_uint(f);
  u = (u + 0x7FFFu + ((u >> 16) & 1u)) >> 16;   // round-to-nearest-even
  return (unsigned short)u;
}

// pack 4 fp32 -> 4 OCP e4m3 bytes (v_cvt_pk_fp8_f32; OCP format on gfx950)
__device__ __forceinline__ unsigned int pk4_fp8(float a, float b, float c,
                                                float d) {
  int u = __builtin_amdgcn_cvt_pk_fp8_f32(a, b, 0, false);   // bytes 0,1
  u = __builtin_amdgcn_cvt_pk_fp8_f32(c, d, u, true);        // bytes 2,3
  return (unsigned int)u;
}

// ---------------------------------------------------------------------------
// Fragment layouts (lane-linear, 512 B per (tile,kk) block):
//  htq (B-operand): block ((hb*16 + otg)*32 + kk), byte quad*128+col*8+j =
//      h[hb][k=kk*32+quad*8+j][o=otg*16+col]
//  wq  (A-operand): block ((hb*64 + rb)*32 + kk), byte quad*128+col*8+j =
//      softmax-weight[row=rb*16+col][k=kk*32+quad*8+j]
// A wave's load/store is base + lane*8: one coalesced 512 B access.
// ---------------------------------------------------------------------------

// ---------------------------------------------------------------------------
// Kernel 0: fp32->bf16 convert of x,W + zero f1/f2 + byte-transposed adj pack.
// adjP per row (128 B): byte [q*32 + kk] = adj bits j = kk*32+q*8 ..+7
// ---------------------------------------------------------------------------
#define CVB  ((XT + WT) / 1024)          // 5120 convert blocks
#define ZRB  128                         // zero blocks
#define PKB  ((B_ * N_ * 32) / 256)      // 1024 adj-pack blocks

__global__ __launch_bounds__(256) void prep(
    const float* __restrict__ x, const float* __restrict__ W,
    const int* __restrict__ adj, unsigned short* __restrict__ xb,
    unsigned short* __restrict__ Wb, float* __restrict__ f12,
    unsigned int* __restrict__ adjP) {
  const int blk = blockIdx.x;
  if (blk >= CVB + ZRB) {    // ---- pack adj (byte-transposed) ----
    const int dw = (blk - CVB - ZRB) * 256 + threadIdx.x;  // permuted dword
    const int r = dw >> 5, pd = dw & 31;
    const int q = pd >> 3, c8 = pd & 7;                    // c8 = kk>>2
    const int* ap = adj + (size_t)r * N_;
    unsigned int out = 0;
#pragma unroll
    for (int i = 0; i < 4; ++i) {        // byte i: kk = c8*4+i
      const int jb = (c8 * 4 + i) * 32 + q * 8;
      int4 v0 = *(const int4*)(ap + jb);
      int4 v1 = *(const int4*)(ap + jb + 4);
      unsigned int byte = 0;
      byte |= (v0.x ? 1u : 0u) << 0; byte |= (v0.y ? 1u : 0u) << 1;
      byte |= (v0.z ? 1u : 0u) << 2; byte |= (v0.w ? 1u : 0u) << 3;
      byte |= (v1.x ? 1u : 0u) << 4; byte |= (v1.y ? 1u : 0u) << 5;
      byte |= (v1.z ? 1u : 0u) << 6; byte |= (v1.w ? 1u : 0u) << 7;
      out |= byte << (i * 8);
    }
    adjP[dw] = out;
    return;
  }
  if (blk >= CVB) {          // ---- zero f1/f2 ----
    const int i = (blk - CVB) * 256 + threadIdx.x;
    ((float4*)f12)[i] = make_float4(0.f, 0.f, 0.f, 0.f);
    return;
  }
  // ---- fp32 -> bf16 ----
  const int i = (blk * 256 + threadIdx.x) * 4;
  const float* src;
  unsigned short* dst;
  int off;
  if (i < XT) { src = x; dst = xb; off = i; }
  else        { src = W; dst = Wb; off = i - XT; }
  float4 v = *(const float4*)(src + off);
  ushort4 s;
  s.x = f2bf(v.x); s.y = f2bf(v.y); s.z = f2bf(v.z); s.w = f2bf(v.w);
  *(ushort4*)(dst + off) = s;
}

// ---------------------------------------------------------------------------
// Kernel 1: projection GEMM, LDS-staged bf16 MFMA, fragment-interleaved fp8
// htq output + fused f1/f2 = h.a1/a2. (unchanged from R9)
// ---------------------------------------------------------------------------
__global__ __launch_bounds__(256) void proj_mfma(
    const unsigned short* __restrict__ xb, const unsigned short* __restrict__ Wb,
    const float* __restrict__ a1, const float* __restrict__ a2,
    unsigned char* __restrict__ htq, float* __restrict__ f1,
    float* __restrict__ f2) {
  __shared__ __align__(16) unsigned short As[128 * 64];  // 16 KB
  __shared__ __align__(16) unsigned short Bs[64 * 64];   //  8 KB
  const int gid = blockIdx.x;
  const int b = gid & 7;
  const int mt_ = (gid >> 3) & 7;
  const int ot_ = (gid >> 6) & 3;
  const int h = gid >> 8;
  const int hb = h * B_ + b;
  const int m0 = mt_ * 128, o0 = ot_ * 64;
  const int t = threadIdx.x, w = t >> 6, lane = t & 63;
  const int col = lane & 15, quad = lane >> 4;

  const int srow = t >> 3;
  const int sslot = t & 7;
  const int sseg = sslot ^ (srow & 7);
  const unsigned short* agp = xb + (size_t)(b * N_ + m0 + srow) * FIN + sseg * 8;
  const unsigned short* bgp = Wb + (size_t)(h * FOUT + o0 + srow) * FIN + sseg * 8;

  f32x4 acc[2][4];
  const f32x4 z4 = {0.f, 0.f, 0.f, 0.f};
#pragma unroll
  for (int mt = 0; mt < 2; ++mt)
#pragma unroll
    for (int ot = 0; ot < 4; ++ot) acc[mt][ot] = z4;

  s16x8 pa[4], pb[2];
#pragma unroll
  for (int i2 = 0; i2 < 4; ++i2) pa[i2] = *(const s16x8*)(agp + (size_t)i2 * 32 * FIN);
#pragma unroll
  for (int i2 = 0; i2 < 2; ++i2) pb[i2] = *(const s16x8*)(bgp + (size_t)i2 * 32 * FIN);

  for (int it = 0; it < FIN / 64; ++it) {
    __syncthreads();
#pragma unroll
    for (int i2 = 0; i2 < 4; ++i2)
      *(s16x8*)&As[(i2 * 32 + srow) * 64 + sslot * 8] = pa[i2];
#pragma unroll
    for (int i2 = 0; i2 < 2; ++i2)
      *(s16x8*)&Bs[(i2 * 32 + srow) * 64 + sslot * 8] = pb[i2];
    __syncthreads();
    if (it < FIN / 64 - 1) {
      const int k0 = (it + 1) * 64;
#pragma unroll
      for (int i2 = 0; i2 < 4; ++i2)
        pa[i2] = *(const s16x8*)(agp + (size_t)i2 * 32 * FIN + k0);
#pragma unroll
      for (int i2 = 0; i2 < 2; ++i2)
        pb[i2] = *(const s16x8*)(bgp + (size_t)i2 * 32 * FIN + k0);
    }
#pragma unroll
    for (int kb = 0; kb < 2; ++kb) {
      s16x8 af[2], bf[4];
#pragma unroll
      for (int mt = 0; mt < 2; ++mt) {
        const int row = w * 32 + mt * 16 + col;
        af[mt] = *(const s16x8*)&As[row * 64 + ((kb * 4 + quad) ^ (row & 7)) * 8];
      }
#pragma unroll
      for (int ot = 0; ot < 4; ++ot) {
        const int row = ot * 16 + col;
        bf[ot] = *(const s16x8*)&Bs[row * 64 + ((kb * 4 + quad) ^ (row & 7)) * 8];
      }
#pragma unroll
      for (int mt = 0; mt < 2; ++mt)
#pragma unroll
        for (int ot = 0; ot < 4; ++ot)
          acc[mt][ot] = __builtin_amdgcn_mfma_f32_16x16x32_bf16(af[mt], bf[ot],
                                                                acc[mt][ot], 0, 0, 0);
    }
  }

  const int kkw = (m0 >> 5) + w;
  float pf1[2][4] = {{0.f}}, pf2[2][4] = {{0.f}};
#pragma unroll
  for (int mt = 0; mt < 2; ++mt) {
#pragma unroll
    for (int ot = 0; ot < 4; ++ot) {
      const int o = o0 + ot * 16 + col;
      const float va1 = a1[h * FOUT + o], va2 = a2[h * FOUT + o];
      const int otg = (o0 >> 4) + ot;
      unsigned char* fb =
          htq + (((size_t)(hb * 16 + otg) * 32 + kkw) << 9);
      const unsigned int q =
          pk4_fp8(acc[mt][ot][0], acc[mt][ot][1], acc[mt][ot][2], acc[mt][ot][3]);
      *(unsigned int*)(fb + (2 * mt + (quad >> 1)) * 128 + col * 8 +
                       (quad & 1) * 4) = q;
#pragma unroll
      for (int r = 0; r < 4; ++r) {
        pf1[mt][r] += acc[mt][ot][r] * va1;
        pf2[mt][r] += acc[mt][ot][r] * va2;
      }
    }
  }
#pragma unroll
  for (int off = 1; off <= 8; off <<= 1)
#pragma unroll
    for (int mt = 0; mt < 2; ++mt)
#pragma unroll
      for (int r = 0; r < 4; ++r) {
        pf1[mt][r] += __shfl_xor(pf1[mt][r], off);
        pf2[mt][r] += __shfl_xor(pf2[mt][r], off);
      }
  if (col == 0) {
#pragma unroll
    for (int mt = 0; mt < 2; ++mt)
#pragma unroll
      for (int r = 0; r < 4; ++r) {
        const int n = m0 + w * 32 + mt * 16 + quad * 4 + r;
        atomicAdd(&f1[hb * N_ + n], pf1[mt][r]);
        atomicAdd(&f2[hb * N_ + n], pf2[mt][r]);
      }
  }
}

// ---------------------------------------------------------------------------
// Kernel 2: wgen — softmax weights -> fp8, written in A-fragment layout.
// Pure streaming VALU + coalesced 512 B stores. No LDS, no barriers.
// Wave task = (hb, rowblock rb, kk-half). Grid 2048 x 256 thr: 8 blk/CU.
// M2 (f2 row max) computed per wave (cheap: 16 loads + 6 shfl).
// ---------------------------------------------------------------------------
__global__ __launch_bounds__(256) void wgen(
    const float* __restrict__ f1, const float* __restrict__ f2,
    const unsigned int* __restrict__ adjP, unsigned char* __restrict__ wq) {
  const int id = blockIdx.x;
  const int b = id & 7, h = (id >> 3) & 7;
  const int rbg = (id >> 6) & 15;
  const int kkh = id >> 10;            // kk half: [kkh*16, +16)
  const int w = threadIdx.x >> 6, lane = threadIdx.x & 63;
  const int col = lane & 15, quad = lane >> 4;
  const int hb = h * B_ + b;
  const int rb = rbg * 4 + w;
  const int row = rb * 16 + col;

  // per-wave M2 = max_j f2[hb][j]
  const float* f2r = f2 + (size_t)hb * N_;
  float m2 = -3.0e38f;
#pragma unroll
  for (int c = 0; c < 16; ++c) m2 = fmaxf(m2, f2r[lane + c * 64]);
#pragma unroll
  for (int off = 32; off; off >>= 1) m2 = fmaxf(m2, __shfl_xor(m2, off));

  const float f1i = f1[(size_t)hb * N_ + row];
  const float tb = f1i + m2;
  const float mhat = fmaxf(tb, ALPHA * tb);   // >= leaky(f1i+f2j) for all j

  const unsigned int* adp = adjP + ((size_t)(b * N_ + row) << 5) + quad * 8;
  const float* f2p = f2r + quad * 8;
  unsigned char* wp = wq + (((size_t)(hb * 64 + rb) * 32) << 9) + lane * 8;

#pragma unroll
  for (int k4i = 0; k4i < 4; ++k4i) {
    const int k4 = kkh * 4 + k4i;
    const unsigned int ad = adp[k4];
#pragma unroll
    for (int k2 = 0; k2 < 4; ++k2) {
      const int kk = k4 * 4 + k2;
      const unsigned int ab = (ad >> (k2 * 8)) & 0xFFu;
      const float4 fA = *(const float4*)(f2p + kk * 32);
      const float4 fB = *(const float4*)(f2p + kk * 32 + 4);
      float ex[8];
#pragma unroll
      for (int j = 0; j < 8; ++j) {
        const float fv = j < 4 ? ((const float*)&fA)[j]
                               : ((const float*)&fB)[j - 4];
        const float tt = f1i + fv;
        const float l = fmaxf(tt, ALPHA * tt);
        const float p = __expf(l - mhat);
        ex[j] = ((ab >> j) & 1u) ? p : 0.f;
      }
      const unsigned int lo = pk4_fp8(ex[0], ex[1], ex[2], ex[3]);
      const unsigned int hi = pk4_fp8(ex[4], ex[5], ex[6], ex[7]);
      *(uint2*)(wp + kk * 512) = make_uint2(lo, hi);
    }
  }
}

// ---------------------------------------------------------------------------
// Kernel 3: pv — pure fp8 MFMA GEMM. A = wq fragments, B = htq fragments,
// ones-column gives softmax denominators. ELU + 2-head sum epilogue.
// Block 256 thr = 4 waves; wave: 16 rows x 64 o-cols x 2 heads.
// Grid 2048 = (b, 4 head-pairs, 4 o-quarters, 16 row-groups): 8 blk/CU.
// ---------------------------------------------------------------------------
__global__ __launch_bounds__(256) void pv(
    const unsigned char* __restrict__ htq, const unsigned char* __restrict__ wq,
    float* __restrict__ p0, float* __restrict__ p1, float* __restrict__ p2,
    float* __restrict__ p3) {
  const int id = blockIdx.x;
  const int b = id & 7;                // XCD-keyed
  const int g0 = (id >> 3) & 3;        // heads {2g0, 2g0+1}
  const int oq = (id >> 5) & 3;        // o-quarter: otg in [oq*4, +4)
  const int it = id >> 7;              // 0..15 (64-row groups)
  const int w = threadIdx.x >> 6, lane = threadIdx.x & 63;
  const int col = lane & 15, quad = lane >> 4;
  const int rb = it * 4 + w;           // this wave's 16-row block

  float hsum[4][4];
#pragma unroll
  for (int t = 0; t < 4; ++t)
#pragma unroll
    for (int r = 0; r < 4; ++r) hsum[t][r] = 0.f;

  const long ones = 0x3838383838383838L;   // 8x fp8 e4m3 1.0

  for (int hh = 0; hh < 2; ++hh) {
    const int hb = (g0 * 2 + hh) * B_ + b;
    const unsigned char* ap = wq + (((size_t)(hb * 64 + rb) * 32) << 9) + lane * 8;
    const unsigned char* bp =
        htq + (((size_t)(hb * 16 + oq * 4) * 32) << 9) + lane * 8;

    f32x4 acc[4], accs;
    const f32x4 z4 = {0.f, 0.f, 0.f, 0.f};
    accs = z4;
#pragma unroll
    for (int t = 0; t < 4; ++t) acc[t] = z4;

#pragma unroll 4
    for (int kk = 0; kk < 32; ++kk) {
      const long af = *(const long*)(ap + kk * 512);
      accs = __builtin_amdgcn_mfma_f32_16x16x32_fp8_fp8(af, ones, accs, 0, 0, 0);
#pragma unroll
      for (int t = 0; t < 4; ++t) {
        const long bf = *(const long*)(bp + ((t * 32 + kk) << 9));
        acc[t] = __builtin_amdgcn_mfma_f32_16x16x32_fp8_fp8(af, bf, acc[t],
                                                            0, 0, 0);
      }
    }

    // normalize (denom = ones-column, same quantized weights), ELU, head-sum
#pragma unroll
    for (int r = 0; r < 4; ++r) {
      const float inv = 1.0f / accs[r];
#pragma unroll
      for (int t = 0; t < 4; ++t) {
        const float oh = acc[t][r] * inv;
        hsum[t][r] += oh > 0.f ? oh : __expf(oh) - 1.f;
      }
    }
  }

  // ---- write head-pair partial: row rb*16+quad*4+r, col oq*64+t*16+col ----
  float* pdst = (g0 == 0) ? p0 : (g0 == 1) ? p1 : (g0 == 2) ? p2 : p3;
#pragma unroll
  for (int t = 0; t < 4; ++t)
#pragma unroll
    for (int r = 0; r < 4; ++r) {
      const int orow = rb * 16 + quad * 4 + r;
      pdst[(size_t)(b * N_ + orow) * FOUT + oq * 64 + t * 16 + col] =
          hsum[t][r];
    }
}

// ---------------------------------------------------------------------------
// Kernel 4: sum 4 head-pair partials + log_softmax over o. Wave per row.
// ---------------------------------------------------------------------------
__global__ __launch_bounds__(256) void logsm(
    const float* __restrict__ p0, const float* __restrict__ p1,
    const float* __restrict__ p2, const float* __restrict__ p3,
    float* __restrict__ out) {
  const int row = blockIdx.x * 4 + (threadIdx.x >> 6);
  const int lane = threadIdx.x & 63;
  const size_t base = (size_t)row * FOUT;
  float v[4];
  float m = -3.0e38f;
#pragma unroll
  for (int c = 0; c < 4; ++c) {
    const size_t idx = base + c * 64 + lane;
    v[c] = p0[idx] + p1[idx] + p2[idx] + p3[idx];
    m = fmaxf(m, v[c]);
  }
#pragma unroll
  for (int off = 32; off; off >>= 1) m = fmaxf(m, __shfl_xor(m, off));
  float s = 0.f;
#pragma unroll
  for (int c = 0; c < 4; ++c) s += __expf(v[c] - m);
#pragma unroll
  for (int off = 32; off; off >>= 1) s += __shfl_xor(s, off);
  const float lg = m + logf(s);
#pragma unroll
  for (int c = 0; c < 4; ++c)
    out[base + c * 64 + lane] = v[c] - lg;
}

// ---------------------------------------------------------------------------
extern "C" void kernel_launch(void* const* d_in, const int* in_sizes, int n_in,
                              void* d_out, int out_size, void* d_ws,
                              size_t ws_size, hipStream_t stream) {
  const float* x   = (const float*)d_in[0];
  const int*   adj = (const int*)d_in[1];
  const float* W   = (const float*)d_in[2];
  const float* a1  = (const float*)d_in[3];
  const float* a2  = (const float*)d_in[4];
  float* out = (float*)d_out;

  unsigned char* htq = (unsigned char*)d_ws;                          // 16 MB fp8 h (frag)
  unsigned short* xb = (unsigned short*)(htq + (size_t)H_ * B_ * FOUT * N_); // 8 MB
  unsigned short* Wb = xb + (size_t)XT;                               // 2 MB
  float* f1 = (float*)(Wb + (size_t)WT);                              // 256 KB
  float* f2 = f1 + (size_t)H_ * B_ * N_;                              // 256 KB
  float* part2 = f2 + (size_t)H_ * B_ * N_;                           // 8 MB
  float* part3 = part2 + (size_t)B_ * N_ * FOUT;                      // 8 MB
  unsigned int* adjP = (unsigned int*)(part3 + (size_t)B_ * N_ * FOUT); // 1 MB
  unsigned char* wq = (unsigned char*)(adjP + (size_t)B_ * N_ * 32);  // 64 MB fp8 weights
  float* part1 = (float*)xb;   // xb dead after proj_mfma (8 MB reuse)

  prep<<<CVB + ZRB + PKB, 256, 0, stream>>>(x, W, adj, xb, Wb, f1, adjP);

  proj_mfma<<<2048, 256, 0, stream>>>(xb, Wb, a1, a2, htq, f1, f2);

  wgen<<<2048, 256, 0, stream>>>(f1, f2, adjP, wq);

  pv<<<2048, 256, 0, stream>>>(htq, wq, out, part1, part2, part3);

  logsm<<<(B_ * N_) / 4, 256, 0, stream>>>(out, part1, part2, part3, out);
}

// Round 11
// 210.444 us; speedup vs baseline: 1.8602x; 1.1158x over previous
//
#include <hip/hip_runtime.h>
#include <math.h>

#define B_    8
#define N_    1024
#define FIN   512
#define FOUT  256
#define H_    8
#define ALPHA 0.2f

#define XT (B_ * N_ * FIN)     // 4194304 x elements
#define WT (H_ * FOUT * FIN)   // 1048576 W elements

typedef short s16x8 __attribute__((ext_vector_type(8)));
typedef float f32x4 __attribute__((ext_vector_type(4)));

__device__ __forceinline__ unsigned short f2bf(float f) {
  unsigned int u = __float_as_uint(f);
  u = (u + 0x7FFFu + ((u >> 16) & 1u)) >> 16;   // round-to-nearest-even
  return (unsigned short)u;
}

// pack 4 fp32 -> 4 OCP e4m3 bytes (v_cvt_pk_fp8_f32; OCP format on gfx950)
__device__ __forceinline__ unsigned int pk4_fp8(float a, float b, float c,
                                                float d) {
  int u = __builtin_amdgcn_cvt_pk_fp8_f32(a, b, 0, false);   // bytes 0,1
  u = __builtin_amdgcn_cvt_pk_fp8_f32(c, d, u, true);        // bytes 2,3
  return (unsigned int)u;
}

// ---------------------------------------------------------------------------
// Fragment layouts (lane-linear, 512 B per (tile,kk) block):
//  htq (B-operand): block ((hb*16 + otg)*32 + kk), byte quad*128+col*8+j =
//      h[hb][k=kk*32+quad*8+j][o=otg*16+col]
//  wq  (A-operand): block ((hb*64 + rb)*32 + kk), byte quad*128+col*8+j =
//      softmax-weight[row=rb*16+col][k=kk*32+quad*8+j]
// A wave's load/store is base + lane*8: one coalesced 512 B access.
// ---------------------------------------------------------------------------

// ---------------------------------------------------------------------------
// Kernel 0: fp32->bf16 convert of x,W + zero f1/f2 + byte-transposed adj pack.
// adjP per row (128 B): byte [q*32 + kk] = adj bits j = kk*32+q*8 ..+7
// ---------------------------------------------------------------------------
#define CVB  ((XT + WT) / 1024)          // 5120 convert blocks
#define ZRB  128                         // zero blocks
#define PKB  ((B_ * N_ * 32) / 256)      // 1024 adj-pack blocks

__global__ __launch_bounds__(256) void prep(
    const float* __restrict__ x, const float* __restrict__ W,
    const int* __restrict__ adj, unsigned short* __restrict__ xb,
    unsigned short* __restrict__ Wb, float* __restrict__ f12,
    unsigned int* __restrict__ adjP) {
  const int blk = blockIdx.x;
  if (blk >= CVB + ZRB) {    // ---- pack adj (byte-transposed) ----
    const int dw = (blk - CVB - ZRB) * 256 + threadIdx.x;  // permuted dword
    const int r = dw >> 5, pd = dw & 31;
    const int q = pd >> 3, c8 = pd & 7;                    // c8 = kk>>2
    const int* ap = adj + (size_t)r * N_;
    unsigned int out = 0;
#pragma unroll
    for (int i = 0; i < 4; ++i) {        // byte i: kk = c8*4+i
      const int jb = (c8 * 4 + i) * 32 + q * 8;
      int4 v0 = *(const int4*)(ap + jb);
      int4 v1 = *(const int4*)(ap + jb + 4);
      unsigned int byte = 0;
      byte |= (v0.x ? 1u : 0u) << 0; byte |= (v0.y ? 1u : 0u) << 1;
      byte |= (v0.z ? 1u : 0u) << 2; byte |= (v0.w ? 1u : 0u) << 3;
      byte |= (v1.x ? 1u : 0u) << 4; byte |= (v1.y ? 1u : 0u) << 5;
      byte |= (v1.z ? 1u : 0u) << 6; byte |= (v1.w ? 1u : 0u) << 7;
      out |= byte << (i * 8);
    }
    adjP[dw] = out;
    return;
  }
  if (blk >= CVB) {          // ---- zero f1/f2 ----
    const int i = (blk - CVB) * 256 + threadIdx.x;
    ((float4*)f12)[i] = make_float4(0.f, 0.f, 0.f, 0.f);
    return;
  }
  // ---- fp32 -> bf16 ----
  const int i = (blk * 256 + threadIdx.x) * 4;
  const float* src;
  unsigned short* dst;
  int off;
  if (i < XT) { src = x; dst = xb; off = i; }
  else        { src = W; dst = Wb; off = i - XT; }
  float4 v = *(const float4*)(src + off);
  ushort4 s;
  s.x = f2bf(v.x); s.y = f2bf(v.y); s.z = f2bf(v.z); s.w = f2bf(v.w);
  *(ushort4*)(dst + off) = s;
}

// ---------------------------------------------------------------------------
// Kernel 1: projection GEMM, LDS-staged bf16 MFMA, fragment-interleaved fp8
// htq output + fused f1/f2 = h.a1/a2. (unchanged from R9)
// ---------------------------------------------------------------------------
__global__ __launch_bounds__(256) void proj_mfma(
    const unsigned short* __restrict__ xb, const unsigned short* __restrict__ Wb,
    const float* __restrict__ a1, const float* __restrict__ a2,
    unsigned char* __restrict__ htq, float* __restrict__ f1,
    float* __restrict__ f2) {
  __shared__ __align__(16) unsigned short As[128 * 64];  // 16 KB
  __shared__ __align__(16) unsigned short Bs[64 * 64];   //  8 KB
  const int gid = blockIdx.x;
  const int b = gid & 7;
  const int mt_ = (gid >> 3) & 7;
  const int ot_ = (gid >> 6) & 3;
  const int h = gid >> 8;
  const int hb = h * B_ + b;
  const int m0 = mt_ * 128, o0 = ot_ * 64;
  const int t = threadIdx.x, w = t >> 6, lane = t & 63;
  const int col = lane & 15, quad = lane >> 4;

  const int srow = t >> 3;
  const int sslot = t & 7;
  const int sseg = sslot ^ (srow & 7);
  const unsigned short* agp = xb + (size_t)(b * N_ + m0 + srow) * FIN + sseg * 8;
  const unsigned short* bgp = Wb + (size_t)(h * FOUT + o0 + srow) * FIN + sseg * 8;

  f32x4 acc[2][4];
  const f32x4 z4 = {0.f, 0.f, 0.f, 0.f};
#pragma unroll
  for (int mt = 0; mt < 2; ++mt)
#pragma unroll
    for (int ot = 0; ot < 4; ++ot) acc[mt][ot] = z4;

  s16x8 pa[4], pb[2];
#pragma unroll
  for (int i2 = 0; i2 < 4; ++i2) pa[i2] = *(const s16x8*)(agp + (size_t)i2 * 32 * FIN);
#pragma unroll
  for (int i2 = 0; i2 < 2; ++i2) pb[i2] = *(const s16x8*)(bgp + (size_t)i2 * 32 * FIN);

  for (int it = 0; it < FIN / 64; ++it) {
    __syncthreads();
#pragma unroll
    for (int i2 = 0; i2 < 4; ++i2)
      *(s16x8*)&As[(i2 * 32 + srow) * 64 + sslot * 8] = pa[i2];
#pragma unroll
    for (int i2 = 0; i2 < 2; ++i2)
      *(s16x8*)&Bs[(i2 * 32 + srow) * 64 + sslot * 8] = pb[i2];
    __syncthreads();
    if (it < FIN / 64 - 1) {
      const int k0 = (it + 1) * 64;
#pragma unroll
      for (int i2 = 0; i2 < 4; ++i2)
        pa[i2] = *(const s16x8*)(agp + (size_t)i2 * 32 * FIN + k0);
#pragma unroll
      for (int i2 = 0; i2 < 2; ++i2)
        pb[i2] = *(const s16x8*)(bgp + (size_t)i2 * 32 * FIN + k0);
    }
#pragma unroll
    for (int kb = 0; kb < 2; ++kb) {
      s16x8 af[2], bf[4];
#pragma unroll
      for (int mt = 0; mt < 2; ++mt) {
        const int row = w * 32 + mt * 16 + col;
        af[mt] = *(const s16x8*)&As[row * 64 + ((kb * 4 + quad) ^ (row & 7)) * 8];
      }
#pragma unroll
      for (int ot = 0; ot < 4; ++ot) {
        const int row = ot * 16 + col;
        bf[ot] = *(const s16x8*)&Bs[row * 64 + ((kb * 4 + quad) ^ (row & 7)) * 8];
      }
#pragma unroll
      for (int mt = 0; mt < 2; ++mt)
#pragma unroll
        for (int ot = 0; ot < 4; ++ot)
          acc[mt][ot] = __builtin_amdgcn_mfma_f32_16x16x32_bf16(af[mt], bf[ot],
                                                                acc[mt][ot], 0, 0, 0);
    }
  }

  const int kkw = (m0 >> 5) + w;
  float pf1[2][4] = {{0.f}}, pf2[2][4] = {{0.f}};
#pragma unroll
  for (int mt = 0; mt < 2; ++mt) {
#pragma unroll
    for (int ot = 0; ot < 4; ++ot) {
      const int o = o0 + ot * 16 + col;
      const float va1 = a1[h * FOUT + o], va2 = a2[h * FOUT + o];
      const int otg = (o0 >> 4) + ot;
      unsigned char* fb =
          htq + (((size_t)(hb * 16 + otg) * 32 + kkw) << 9);
      const unsigned int q =
          pk4_fp8(acc[mt][ot][0], acc[mt][ot][1], acc[mt][ot][2], acc[mt][ot][3]);
      *(unsigned int*)(fb + (2 * mt + (quad >> 1)) * 128 + col * 8 +
                       (quad & 1) * 4) = q;
#pragma unroll
      for (int r = 0; r < 4; ++r) {
        pf1[mt][r] += acc[mt][ot][r] * va1;
        pf2[mt][r] += acc[mt][ot][r] * va2;
      }
    }
  }
#pragma unroll
  for (int off = 1; off <= 8; off <<= 1)
#pragma unroll
    for (int mt = 0; mt < 2; ++mt)
#pragma unroll
      for (int r = 0; r < 4; ++r) {
        pf1[mt][r] += __shfl_xor(pf1[mt][r], off);
        pf2[mt][r] += __shfl_xor(pf2[mt][r], off);
      }
  if (col == 0) {
#pragma unroll
    for (int mt = 0; mt < 2; ++mt)
#pragma unroll
      for (int r = 0; r < 4; ++r) {
        const int n = m0 + w * 32 + mt * 16 + quad * 4 + r;
        atomicAdd(&f1[hb * N_ + n], pf1[mt][r]);
        atomicAdd(&f2[hb * N_ + n], pf2[mt][r]);
      }
  }
}

// ---------------------------------------------------------------------------
// Kernel 2: wgen — softmax weights -> fp8, written in A-fragment layout.
// (unchanged from R10)
// ---------------------------------------------------------------------------
__global__ __launch_bounds__(256) void wgen(
    const float* __restrict__ f1, const float* __restrict__ f2,
    const unsigned int* __restrict__ adjP, unsigned char* __restrict__ wq) {
  const int id = blockIdx.x;
  const int b = id & 7, h = (id >> 3) & 7;
  const int rbg = (id >> 6) & 15;
  const int kkh = id >> 10;            // kk half: [kkh*16, +16)
  const int w = threadIdx.x >> 6, lane = threadIdx.x & 63;
  const int col = lane & 15, quad = lane >> 4;
  const int hb = h * B_ + b;
  const int rb = rbg * 4 + w;
  const int row = rb * 16 + col;

  // per-wave M2 = max_j f2[hb][j]
  const float* f2r = f2 + (size_t)hb * N_;
  float m2 = -3.0e38f;
#pragma unroll
  for (int c = 0; c < 16; ++c) m2 = fmaxf(m2, f2r[lane + c * 64]);
#pragma unroll
  for (int off = 32; off; off >>= 1) m2 = fmaxf(m2, __shfl_xor(m2, off));

  const float f1i = f1[(size_t)hb * N_ + row];
  const float tb = f1i + m2;
  const float mhat = fmaxf(tb, ALPHA * tb);   // >= leaky(f1i+f2j) for all j

  const unsigned int* adp = adjP + ((size_t)(b * N_ + row) << 5) + quad * 8;
  const float* f2p = f2r + quad * 8;
  unsigned char* wp = wq + (((size_t)(hb * 64 + rb) * 32) << 9) + lane * 8;

#pragma unroll
  for (int k4i = 0; k4i < 4; ++k4i) {
    const int k4 = kkh * 4 + k4i;
    const unsigned int ad = adp[k4];
#pragma unroll
    for (int k2 = 0; k2 < 4; ++k2) {
      const int kk = k4 * 4 + k2;
      const unsigned int ab = (ad >> (k2 * 8)) & 0xFFu;
      const float4 fA = *(const float4*)(f2p + kk * 32);
      const float4 fB = *(const float4*)(f2p + kk * 32 + 4);
      float ex[8];
#pragma unroll
      for (int j = 0; j < 8; ++j) {
        const float fv = j < 4 ? ((const float*)&fA)[j]
                               : ((const float*)&fB)[j - 4];
        const float tt = f1i + fv;
        const float l = fmaxf(tt, ALPHA * tt);
        const float p = __expf(l - mhat);
        ex[j] = ((ab >> j) & 1u) ? p : 0.f;
      }
      const unsigned int lo = pk4_fp8(ex[0], ex[1], ex[2], ex[3]);
      const unsigned int hi = pk4_fp8(ex[4], ex[5], ex[6], ex[7]);
      *(uint2*)(wp + kk * 512) = make_uint2(lo, hi);
    }
  }
}

// ---------------------------------------------------------------------------
// Kernel 3: pv — pure fp8 MFMA GEMM, FAT TILE: wave = 32 rows x 64 cols
// x 2 heads. Per kk: 6 loads (2 A + 4 B) feeding 10 MFMAs (50 cyc of MFMA
// per load group — 2x the R10 intensity; B L2 traffic halved).
// Grid 1024 = (b, 4 head-pairs, 4 o-quarters, 8 row-groups): 4 blk/CU,
// 16 waves/CU at ~100 VGPR (launch_bounds(256,4): cap 128, no spill).
// ---------------------------------------------------------------------------
__global__ __launch_bounds__(256, 4) void pv(
    const unsigned char* __restrict__ htq, const unsigned char* __restrict__ wq,
    float* __restrict__ p0, float* __restrict__ p1, float* __restrict__ p2,
    float* __restrict__ p3) {
  const int id = blockIdx.x;
  const int b = id & 7;                // XCD-keyed
  const int g0 = (id >> 3) & 3;        // heads {2g0, 2g0+1}
  const int oq = (id >> 5) & 3;        // o-quarter: otg in [oq*4, +4)
  const int it = id >> 7;              // 0..7 (128-row groups)
  const int w = threadIdx.x >> 6, lane = threadIdx.x & 63;
  const int col = lane & 15, quad = lane >> 4;
  const int rb = it * 8 + w * 2;       // this wave's rows [rb*16, rb*16+32)

  float hsum[2][4][4];
#pragma unroll
  for (int g = 0; g < 2; ++g)
#pragma unroll
    for (int t = 0; t < 4; ++t)
#pragma unroll
      for (int r = 0; r < 4; ++r) hsum[g][t][r] = 0.f;

  const long ones = 0x3838383838383838L;   // 8x fp8 e4m3 1.0

  for (int hh = 0; hh < 2; ++hh) {
    const int hb = (g0 * 2 + hh) * B_ + b;
    const unsigned char* ap =
        wq + (((size_t)(hb * 64 + rb) * 32) << 9) + lane * 8;
    const unsigned char* bp =
        htq + (((size_t)(hb * 16 + oq * 4) * 32) << 9) + lane * 8;

    f32x4 acc[2][4], accs[2];
    const f32x4 z4 = {0.f, 0.f, 0.f, 0.f};
#pragma unroll
    for (int g = 0; g < 2; ++g) {
      accs[g] = z4;
#pragma unroll
      for (int t = 0; t < 4; ++t) acc[g][t] = z4;
    }

#pragma unroll 2
    for (int kk = 0; kk < 32; ++kk) {
      const long af0 = *(const long*)(ap + kk * 512);
      const long af1 = *(const long*)(ap + 16384 + kk * 512);  // block rb+1
      accs[0] = __builtin_amdgcn_mfma_f32_16x16x32_fp8_fp8(af0, ones, accs[0], 0, 0, 0);
      accs[1] = __builtin_amdgcn_mfma_f32_16x16x32_fp8_fp8(af1, ones, accs[1], 0, 0, 0);
#pragma unroll
      for (int t = 0; t < 4; ++t) {
        const long bf = *(const long*)(bp + ((t * 32 + kk) << 9));
        acc[0][t] = __builtin_amdgcn_mfma_f32_16x16x32_fp8_fp8(af0, bf,
                                                               acc[0][t], 0, 0, 0);
        acc[1][t] = __builtin_amdgcn_mfma_f32_16x16x32_fp8_fp8(af1, bf,
                                                               acc[1][t], 0, 0, 0);
      }
    }

    // normalize (denom = ones-column, same quantized weights), ELU, head-sum
#pragma unroll
    for (int g = 0; g < 2; ++g)
#pragma unroll
      for (int r = 0; r < 4; ++r) {
        const float inv = 1.0f / accs[g][r];
#pragma unroll
        for (int t = 0; t < 4; ++t) {
          const float oh = acc[g][t][r] * inv;
          hsum[g][t][r] += oh > 0.f ? oh : __expf(oh) - 1.f;
        }
      }
  }

  // ---- write head-pair partial: row (rb+g)*16+quad*4+r, col oq*64+t*16+col
  float* pdst = (g0 == 0) ? p0 : (g0 == 1) ? p1 : (g0 == 2) ? p2 : p3;
#pragma unroll
  for (int g = 0; g < 2; ++g)
#pragma unroll
    for (int t = 0; t < 4; ++t)
#pragma unroll
      for (int r = 0; r < 4; ++r) {
        const int orow = (rb + g) * 16 + quad * 4 + r;
        pdst[(size_t)(b * N_ + orow) * FOUT + oq * 64 + t * 16 + col] =
            hsum[g][t][r];
      }
}

// ---------------------------------------------------------------------------
// Kernel 4: sum 4 head-pair partials + log_softmax over o. Wave per row.
// ---------------------------------------------------------------------------
__global__ __launch_bounds__(256) void logsm(
    const float* __restrict__ p0, const float* __restrict__ p1,
    const float* __restrict__ p2, const float* __restrict__ p3,
    float* __restrict__ out) {
  const int row = blockIdx.x * 4 + (threadIdx.x >> 6);
  const int lane = threadIdx.x & 63;
  const size_t base = (size_t)row * FOUT;
  float v[4];
  float m = -3.0e38f;
#pragma unroll
  for (int c = 0; c < 4; ++c) {
    const size_t idx = base + c * 64 + lane;
    v[c] = p0[idx] + p1[idx] + p2[idx] + p3[idx];
    m = fmaxf(m, v[c]);
  }
#pragma unroll
  for (int off = 32; off; off >>= 1) m = fmaxf(m, __shfl_xor(m, off));
  float s = 0.f;
#pragma unroll
  for (int c = 0; c < 4; ++c) s += __expf(v[c] - m);
#pragma unroll
  for (int off = 32; off; off >>= 1) s += __shfl_xor(s, off);
  const float lg = m + logf(s);
#pragma unroll
  for (int c = 0; c < 4; ++c)
    out[base + c * 64 + lane] = v[c] - lg;
}

// ---------------------------------------------------------------------------
extern "C" void kernel_launch(void* const* d_in, const int* in_sizes, int n_in,
                              void* d_out, int out_size, void* d_ws,
                              size_t ws_size, hipStream_t stream) {
  const float* x   = (const float*)d_in[0];
  const int*   adj = (const int*)d_in[1];
  const float* W   = (const float*)d_in[2];
  const float* a1  = (const float*)d_in[3];
  const float* a2  = (const float*)d_in[4];
  float* out = (float*)d_out;

  unsigned char* htq = (unsigned char*)d_ws;                          // 16 MB fp8 h (frag)
  unsigned short* xb = (unsigned short*)(htq + (size_t)H_ * B_ * FOUT * N_); // 8 MB
  unsigned short* Wb = xb + (size_t)XT;                               // 2 MB
  float* f1 = (float*)(Wb + (size_t)WT);                              // 256 KB
  float* f2 = f1 + (size_t)H_ * B_ * N_;                              // 256 KB
  float* part2 = f2 + (size_t)H_ * B_ * N_;                           // 8 MB
  float* part3 = part2 + (size_t)B_ * N_ * FOUT;                      // 8 MB
  unsigned int* adjP = (unsigned int*)(part3 + (size_t)B_ * N_ * FOUT); // 1 MB
  unsigned char* wq = (unsigned char*)(adjP + (size_t)B_ * N_ * 32);  // 64 MB fp8 weights
  float* part1 = (float*)xb;   // xb dead after proj_mfma (8 MB reuse)

  prep<<<CVB + ZRB + PKB, 256, 0, stream>>>(x, W, adj, xb, Wb, f1, adjP);

  proj_mfma<<<2048, 256, 0, stream>>>(xb, Wb, a1, a2, htq, f1, f2);

  wgen<<<2048, 256, 0, stream>>>(f1, f2, adjP, wq);

  pv<<<1024, 256, 0, stream>>>(htq, wq, out, part1, part2, part3);

  logsm<<<(B_ * N_) / 4, 256, 0, stream>>>(out, part1, part2, part3, out);
}